// Round 6
// baseline (322.189 us; speedup 1.0000x reference)
//
#include <hip/hip_runtime.h>
#include <hip/hip_fp16.h>

#define N_NODES   50000
#define N_EDGES   800000
#define D         64
#define N_CLASSES 10
#define N_GRAPHS  128
#define ELLW      48   // max in-degree bound: Poisson(16), P(any deg>=48) ~ 1e-6; input fixed
#define CPAD      16   // counters padded to one per 64B line (atomic line-serialization fix)
#define NXCD      8
#define DPART     (N_NODES / NXCD)   // 6250 dst nodes per XCD partition

// ELL entry is PACKED 4B: low16 = src node id (<50000<65536), high16 = ew as fp16.
// Activations are stored PRE-SCALED: xwh'[i] = dinv[i] * (h @ W)[i], so the
// gather needs NO per-edge dinv lookup (was ~16 random L2 loads/row, a third
// of the VMEM stream in the latency-bound gather):
//   agg[i] = dv*( xwh'[i] + sum_j ew_j * xwh'[src_j] ) + b

__device__ __forceinline__ float unpack_ew(int p) {
    return __half2float(__ushort_as_half((unsigned short)((unsigned)p >> 16)));
}

// ---------------- setup kernels ----------------

// XCD-partitioned scatter (round-2 proven form: 46.6us, occ 62%). Round-4's
// nontemporal scan REGRESSED (FETCH 37->48MB): nt evicted the 8x-amplified dst
// re-reads from L2 without enabling write merging. The ~31MB residual write
// traffic is structural (~1-2 entries per ELL line per fill window). This is
// the scatter's latency/atomic floor; leave it.
__global__ __launch_bounds__(256) void ell_scatter(const int* __restrict__ src,
                                                   const int* __restrict__ dst,
                                                   const float* __restrict__ ew,
                                                   int* __restrict__ count,
                                                   unsigned int* __restrict__ ell) {
    const int grp = blockIdx.x & (NXCD - 1);
    const int ord = blockIdx.x >> 3;          // 0..390
    const int lo  = grp * DPART;
#pragma unroll
    for (int i = 0; i < 8; ++i) {
        int e = ord * 2048 + i * 256 + threadIdx.x;
        if (e < N_EDGES) {
            int d = dst[e];
            if ((unsigned)(d - lo) < (unsigned)DPART) {
                int s = src[e];
                float w = ew[e];
                int c = atomicAdd(&count[d * CPAD], 1);
                if (c < ELLW) {
                    ell[d * ELLW + c] = (unsigned int)s |
                        ((unsigned int)__half_as_ushort(__float2half_rn(w)) << 16);
                }
            }
        }
    }
}

// Wave per node: deg = 1 + sum(ew over slots), dinv = rsqrt(deg). Atomic-free.
__global__ __launch_bounds__(256) void node_dinv(const int* __restrict__ count,
                                                 const unsigned int* __restrict__ ell,
                                                 float* __restrict__ dinv) {
    const int lane = threadIdx.x & 63;
    const int gwave = (blockIdx.x * blockDim.x + threadIdx.x) >> 6;
    const int nw = (gridDim.x * blockDim.x) >> 6;
    for (int i = gwave; i < N_NODES; i += nw) {
        int cnt = min(count[i * CPAD], ELLW);
        float w = (lane < cnt) ? unpack_ew((int)ell[i * ELLW + lane]) : 0.0f;
#pragma unroll
        for (int off = 32; off >= 1; off >>= 1) w += __shfl_xor(w, off);
        if (lane == 0) dinv[i] = rsqrtf(1.0f + w);
    }
}

// ---------------- shared gather core ----------------

// acc = xwh'[row] + sum_j ew_j * xwh'[src_j]; meta via uniform int4 (4 packed
// edges / 16B broadcast load), 8 fp16 row-gathers outstanding; dinv-free.
__device__ __forceinline__ float gather_acc(const int* __restrict__ count,
                                            const unsigned int* __restrict__ ell,
                                            const __half* __restrict__ xwh,
                                            int row, int lane) {
    int cnt = min(count[row * CPAD], ELLW);
    const int4* m4 = (const int4*)(ell + (size_t)row * ELLW);
    float acc = __half2float(xwh[(size_t)row * D + lane]);  // self-loop (pre-scaled)
    int j = 0;
    for (; j + 8 <= cnt; j += 8) {
        int4 a = m4[j / 4 + 0];  // edges j..j+3 (uniform -> broadcast)
        int4 b = m4[j / 4 + 1];  // edges j+4..j+7
        int p0 = __builtin_amdgcn_readfirstlane(a.x);
        int p1 = __builtin_amdgcn_readfirstlane(a.y);
        int p2 = __builtin_amdgcn_readfirstlane(a.z);
        int p3 = __builtin_amdgcn_readfirstlane(a.w);
        int p4 = __builtin_amdgcn_readfirstlane(b.x);
        int p5 = __builtin_amdgcn_readfirstlane(b.y);
        int p6 = __builtin_amdgcn_readfirstlane(b.z);
        int p7 = __builtin_amdgcn_readfirstlane(b.w);
        float v0 = __half2float(xwh[(size_t)(p0 & 0xFFFF) * D + lane]);
        float v1 = __half2float(xwh[(size_t)(p1 & 0xFFFF) * D + lane]);
        float v2 = __half2float(xwh[(size_t)(p2 & 0xFFFF) * D + lane]);
        float v3 = __half2float(xwh[(size_t)(p3 & 0xFFFF) * D + lane]);
        float v4 = __half2float(xwh[(size_t)(p4 & 0xFFFF) * D + lane]);
        float v5 = __half2float(xwh[(size_t)(p5 & 0xFFFF) * D + lane]);
        float v6 = __half2float(xwh[(size_t)(p6 & 0xFFFF) * D + lane]);
        float v7 = __half2float(xwh[(size_t)(p7 & 0xFFFF) * D + lane]);
        acc = fmaf(v0, unpack_ew(p0), acc);
        acc = fmaf(v1, unpack_ew(p1), acc);
        acc = fmaf(v2, unpack_ew(p2), acc);
        acc = fmaf(v3, unpack_ew(p3), acc);
        acc = fmaf(v4, unpack_ew(p4), acc);
        acc = fmaf(v5, unpack_ew(p5), acc);
        acc = fmaf(v6, unpack_ew(p6), acc);
        acc = fmaf(v7, unpack_ew(p7), acc);
    }
    for (; j + 4 <= cnt; j += 4) {
        int4 a = m4[j / 4];
        int p0 = __builtin_amdgcn_readfirstlane(a.x);
        int p1 = __builtin_amdgcn_readfirstlane(a.y);
        int p2 = __builtin_amdgcn_readfirstlane(a.z);
        int p3 = __builtin_amdgcn_readfirstlane(a.w);
        float v0 = __half2float(xwh[(size_t)(p0 & 0xFFFF) * D + lane]);
        float v1 = __half2float(xwh[(size_t)(p1 & 0xFFFF) * D + lane]);
        float v2 = __half2float(xwh[(size_t)(p2 & 0xFFFF) * D + lane]);
        float v3 = __half2float(xwh[(size_t)(p3 & 0xFFFF) * D + lane]);
        acc = fmaf(v0, unpack_ew(p0), acc);
        acc = fmaf(v1, unpack_ew(p1), acc);
        acc = fmaf(v2, unpack_ew(p2), acc);
        acc = fmaf(v3, unpack_ew(p3), acc);
    }
    for (; j < cnt; ++j) {
        int p = __builtin_amdgcn_readfirstlane((int)ell[(size_t)row * ELLW + j]);
        float v = __half2float(xwh[(size_t)(p & 0xFFFF) * D + lane]);
        acc = fmaf(v, unpack_ew(p), acc);
    }
    return acc;
}

// ---------------- per-layer kernels ----------------

// xwh' = dinv[row] * (in @ W)   (layer 1 only; layers 2,3 fused into aggemm).
// dinv[row] is one uniform load per row. Kept as its OWN dispatch (round-1
// fusion with the scatter collapsed scatter occupancy 52%->9%).
__global__ __launch_bounds__(256) void gemm_rows(const float* __restrict__ in,
                                                 const float* __restrict__ W,
                                                 const float* __restrict__ dinv,
                                                 __half* __restrict__ xwh) {
    __shared__ float Wl[D * D];
    for (int i = threadIdx.x; i < D * D; i += blockDim.x) Wl[i] = W[i];
    __syncthreads();

    const int lane = threadIdx.x & 63;
    float w[D];
#pragma unroll
    for (int k = 0; k < D; ++k) w[k] = Wl[k * D + lane];  // 2-way bank alias: free

    const int gwave = (blockIdx.x * blockDim.x + threadIdx.x) >> 6;
    const int nw = (gridDim.x * blockDim.x) >> 6;
    const int chunk = (N_NODES + nw - 1) / nw;
    int r0 = __builtin_amdgcn_readfirstlane(gwave * chunk);
    int r1 = min(r0 + chunk, N_NODES);

    for (int row = r0; row < r1; ++row) {
        const float4* xr = (const float4*)(in + (size_t)row * D);  // uniform ptr
        float dv = dinv[row];
        float acc = 0.0f;
#pragma unroll
        for (int k4 = 0; k4 < D / 4; ++k4) {
            float4 xv = xr[k4];  // s_load_dwordx4 (uniform)
            acc = fmaf(xv.x, w[4 * k4 + 0], acc);
            acc = fmaf(xv.y, w[4 * k4 + 1], acc);
            acc = fmaf(xv.z, w[4 * k4 + 2], acc);
            acc = fmaf(xv.w, w[4 * k4 + 3], acc);
        }
        xwh[(size_t)row * D + lane] = __float2half(acc * dv);
    }
}

// FUSED agg+gemm (layers 1->2 and 2->3):
//   s    = relu( dv*gather + bias )          (fp32, one value per lane)
//   xout = dv * (s @ W)                      (next layer's pre-scaled xwh')
// Epilogue: s staged in a per-wave LDS row (wave-synchronous, no barrier),
// read back as uniform float4 broadcasts, FMA vs W[k*D+lane] in LDS (2-way
// bank alias: free). W in LDS keeps VGPR ~50 -> occupancy preserved.
__global__ __launch_bounds__(256) void aggemm(const int* __restrict__ count,
                                              const unsigned int* __restrict__ ell,
                                              const float* __restrict__ dinv,
                                              const __half* __restrict__ xin,
                                              const float* __restrict__ bias,
                                              const float* __restrict__ W,
                                              __half* __restrict__ xout) {
    __shared__ float Wl[D * D];       // 16KB
    __shared__ float rb[4][D];        // 1KB: per-wave fp32 row buffer
    for (int i = threadIdx.x; i < D * D; i += blockDim.x) Wl[i] = W[i];
    __syncthreads();

    const int lane = threadIdx.x & 63;
    const int wid  = threadIdx.x >> 6;
    const int gwave = (blockIdx.x * blockDim.x + threadIdx.x) >> 6;
    const int nw = (gridDim.x * blockDim.x) >> 6;
    const float bv = bias[lane];

    for (int row = gwave; row < N_NODES; row += nw) {
        float dv = dinv[row];
        float acc = gather_acc(count, ell, xin, row, lane);
        float s = fmaxf(fmaf(acc, dv, bv), 0.0f);   // fused layers always relu
        rb[wid][lane] = s;
        const float4* r4 = (const float4*)rb[wid];
        float o = 0.0f;
#pragma unroll
        for (int k4 = 0; k4 < D / 4; ++k4) {
            float4 r = r4[k4];  // uniform addr -> LDS broadcast
            o = fmaf(r.x, Wl[(4 * k4 + 0) * D + lane], o);
            o = fmaf(r.y, Wl[(4 * k4 + 1) * D + lane], o);
            o = fmaf(r.z, Wl[(4 * k4 + 2) * D + lane], o);
            o = fmaf(r.w, Wl[(4 * k4 + 3) * D + lane], o);
        }
        xout[(size_t)row * D + lane] = __float2half(o * dv);
    }
}

// Plain aggregation (layer-3 output): agg3 = dv*gather + b3, no relu, fp32.
__global__ __launch_bounds__(256) void node_agg(const int* __restrict__ count,
                                                const unsigned int* __restrict__ ell,
                                                const float* __restrict__ dinv,
                                                const __half* __restrict__ xwh,
                                                const float* __restrict__ bias,
                                                float* __restrict__ agg) {
    const int lane = threadIdx.x & 63;
    const int gwave = (blockIdx.x * blockDim.x + threadIdx.x) >> 6;
    const int nw = (gridDim.x * blockDim.x) >> 6;
    const float bv = bias[lane];

    for (int row = gwave; row < N_NODES; row += nw) {
        float dv = dinv[row];
        float acc = gather_acc(count, ell, xwh, row, lane);
        agg[(size_t)row * D + lane] = fmaf(acc, dv, bv);
    }
}

// ---------------- pooling + classifier ----------------

// batch sorted: contiguous chunk per wave, register accumulate, flush per boundary.
__global__ __launch_bounds__(256) void pool(const float* __restrict__ agg3,
                                            const int* __restrict__ batch,
                                            float* __restrict__ pooled,
                                            float* __restrict__ cnt) {
    const int lane = threadIdx.x & 63;
    const int gwave = (blockIdx.x * blockDim.x + threadIdx.x) >> 6;
    const int nw = (gridDim.x * blockDim.x) >> 6;
    const int chunk = (N_NODES + nw - 1) / nw;
    int r0 = gwave * chunk;
    int r1 = min(r0 + chunk, N_NODES);
    if (r0 >= r1) return;

    int g = batch[r0];
    float acc = 0.0f;
    int c = 0;
    for (int row = r0; row < r1; ++row) {
        int gg = batch[row];
        if (gg != g) {
            atomicAdd(&pooled[g * D + lane], acc);
            if (lane == 0) atomicAdd(&cnt[g], (float)c);
            g = gg; acc = 0.0f; c = 0;
        }
        acc += agg3[(size_t)row * D + lane];
        ++c;
    }
    atomicAdd(&pooled[g * D + lane], acc);
    if (lane == 0) atomicAdd(&cnt[g], (float)c);
}

__global__ __launch_bounds__(64) void final_lin(const float* __restrict__ pooled,
                                                const float* __restrict__ cnt,
                                                const float* __restrict__ Wlin,
                                                const float* __restrict__ blin,
                                                float* __restrict__ out) {
    __shared__ float row[D];
    int g = blockIdx.x;
    int t = threadIdx.x;
    float c = fmaxf(cnt[g], 1.0f);
    row[t] = pooled[g * D + t] / c;
    __syncthreads();
    if (t < N_CLASSES) {
        float acc = blin[t];
#pragma unroll
        for (int k = 0; k < D; ++k) acc = fmaf(row[k], Wlin[k * N_CLASSES + t], acc);
        out[g * N_CLASSES + t] = acc;
    }
}

// ---------------- launch ----------------

extern "C" void kernel_launch(void* const* d_in, const int* in_sizes, int n_in,
                              void* d_out, int out_size, void* d_ws, size_t ws_size,
                              hipStream_t stream) {
    const float* x     = (const float*)d_in[0];
    const int*   ei    = (const int*)d_in[1];
    const int*   src   = ei;
    const int*   dst   = ei + N_EDGES;
    const int*   batch = (const int*)d_in[2];
    const float* ew    = (const float*)d_in[3];
    const float* W1    = (const float*)d_in[4];
    const float* b1    = (const float*)d_in[5];
    const float* W2    = (const float*)d_in[6];
    const float* b2    = (const float*)d_in[7];
    const float* W3    = (const float*)d_in[8];
    const float* b3    = (const float*)d_in[9];
    const float* Wlin  = (const float*)d_in[10];
    const float* blin  = (const float*)d_in[11];
    float* out = (float*)d_out;

    // workspace layout (4B units)
    float*        ws     = (float*)d_ws;
    __half*       xwhA   = (__half*)ws;                    // 50000*64 half = 1,600,000 floats
    __half*       xwhB   = (__half*)(ws + 1600000);        // double buffer (fused layers)
    float*        agg3   = ws + 3200000;                   // 3,200,000 (fp32 layer-3 out)
    unsigned int* ell    = (unsigned int*)(ws + 6400000);  // 50000*48 u32 = 2,400,000 floats
    float*        dinv   = ws + 8800000;                   // 50,000
    int*          count  = (int*)(ws + 8850000);           // 50000*16 = 800,000 (line-padded)
    float*        pooled = ws + 9650000;                   // 8,192
    float*        cnt    = ws + 9658192;                   // 128
    // total ~9.66M * 4B = ~38.6 MB

    const int B = 256;

    (void)hipMemsetAsync(count, 0, N_NODES * CPAD * sizeof(int), stream);
    (void)hipMemsetAsync(pooled, 0, (N_GRAPHS * D + N_GRAPHS) * sizeof(float), stream);

    const int aggBlocks = 3125;  // 12500 waves, 4 nodes each

    // ELL build: 8 groups x 391 blocks; group = bid&7 owns one dst partition.
    ell_scatter<<<391 * NXCD, B, 0, stream>>>(src, dst, ew, count, ell);
    node_dinv<<<aggBlocks, B, 0, stream>>>(count, ell, dinv);

    // layer 1 gemm: xwhA = dinv .* (x @ W1)
    gemm_rows<<<1024, B, 0, stream>>>(x, W1, dinv, xwhA);
    // fused layer 1 agg + layer 2 gemm: xwhB = dinv .* (relu(A^(xwhA)+b1) @ W2)
    aggemm<<<aggBlocks, B, 0, stream>>>(count, ell, dinv, xwhA, b1, W2, xwhB);
    // fused layer 2 agg + layer 3 gemm: xwhA = dinv .* (relu(A^(xwhB)+b2) @ W3)
    aggemm<<<aggBlocks, B, 0, stream>>>(count, ell, dinv, xwhB, b2, W3, xwhA);
    // layer 3 aggregation (no relu): agg3 = A^(xwhA) + b3
    node_agg<<<aggBlocks, B, 0, stream>>>(count, ell, dinv, xwhA, b3, agg3);

    // global mean pool and classifier
    pool<<<196, B, 0, stream>>>(agg3, batch, pooled, cnt);
    final_lin<<<N_GRAPHS, 64, 0, stream>>>(pooled, cnt, Wlin, blin, out);
}